// Round 7
// baseline (2604.126 us; speedup 1.0000x reference)
//
#include <hip/hip_runtime.h>
#include <math.h>

#define DIN   192
#define HD    256
#define ROWS  32
#define THREADS 256
#define LSTR  256

typedef __bf16 bf16_t;
typedef bf16_t bf16x8 __attribute__((ext_vector_type(8)));
typedef unsigned short u16x8 __attribute__((ext_vector_type(8)));
typedef float  f32x16 __attribute__((ext_vector_type(16)));

static __device__ __forceinline__ f32x16 mfma32(bf16x8 a, bf16x8 b, f32x16 c) {
  return __builtin_amdgcn_mfma_f32_32x32x16_bf16(a, b, c, 0, 0, 0);
}
static __device__ __forceinline__ unsigned short f2bfu(float f) {
  bf16_t h = (bf16_t)f; unsigned short u; __builtin_memcpy(&u, &h, 2); return u;
}
static __device__ __forceinline__ float bfu2f(unsigned short u) {
  unsigned x = ((unsigned)u) << 16; float f; __builtin_memcpy(&f, &x, 4); return f;
}
static __device__ __forceinline__ unsigned pk2(float a, float b) {
  return (unsigned)f2bfu(a) | ((unsigned)f2bfu(b) << 16);
}
static __device__ __forceinline__ float lo16(unsigned u) { return bfu2f((unsigned short)(u & 0xffff)); }
static __device__ __forceinline__ float hi16(unsigned u) { return bfu2f((unsigned short)(u >> 16)); }
static __device__ __forceinline__ float sigm(float x) {
  return __builtin_amdgcn_rcpf(1.f + __expf(-x));
}
// XOR-swizzled LDS element index (b16 granularity)
static __device__ __forceinline__ int lidx(int row, int col) {
  return row * LSTR + (col ^ ((row & 7) << 3));
}
// C-layout row for 32x32 MFMA (m74/m101): row = (r&3) + 8*(r>>2) + 4*kg
static __device__ __forceinline__ int crow(int r, int kg) {
  return (r & 3) + 8 * (r >> 2) + 4 * kg;
}

// bf16 weight regions (elements) in d_ws after scores buffer.
// Fragment order: ((tile*KS + ks)*64 + lane)*8 + j; tile=ocol>>5,
// lane=kg*32+(ocol&31), k=ks*16+kg*8+j. out_w padded 4->32 cols.
#define OFF_WSW1 0
#define OFF_WSS1 49152
#define OFF_WSG1 98304
#define OFF_WSC1 147456
#define OFF_WSW2 212992
#define OFF_WSS2 278528
#define OFF_WSG2 344064
#define OFF_WSC2 409600
#define OFF_WOUT 475136
#define NGRP_REORD 59392
#define NGRP_ALL   60416

__global__ void iab_wconv_kernel(const float* __restrict__ a0, const float* __restrict__ a1,
                                 const float* __restrict__ a2, const float* __restrict__ a3,
                                 const float* __restrict__ a4, const float* __restrict__ a5,
                                 const float* __restrict__ a6, const float* __restrict__ a7,
                                 const float* __restrict__ a8, unsigned short* __restrict__ out)
{
  const int i = blockIdx.x * 256 + threadIdx.x;
  if (i >= NGRP_ALL) return;
  if (i >= NGRP_REORD) {                       // out_w padded fragment tile
    const int g  = i - NGRP_REORD;             // [0, 1024)
    const int ks = g >> 6;
    const int ln = g & 63;
    const int col = ln & 31;
    const int kg  = ln >> 5;
    #pragma unroll
    for (int j = 0; j < 8; ++j) {
      const float vv = (col < 4) ? a8[col * 256 + ks * 16 + kg * 8 + j] : 0.f;
      out[OFF_WOUT + (size_t)g * 8 + j] = f2bfu(vv);
    }
    return;
  }
  const float* src; int off, Kd, g;
  if      (i < 6144)  { src = a0; off = OFF_WSW1; Kd = 192; g = i; }
  else if (i < 12288) { src = a1; off = OFF_WSS1; Kd = 192; g = i - 6144; }
  else if (i < 18432) { src = a2; off = OFF_WSG1; Kd = 192; g = i - 12288; }
  else if (i < 26624) { src = a3; off = OFF_WSC1; Kd = 256; g = i - 18432; }
  else if (i < 34816) { src = a4; off = OFF_WSW2; Kd = 256; g = i - 26624; }
  else if (i < 43008) { src = a5; off = OFF_WSS2; Kd = 256; g = i - 34816; }
  else if (i < 51200) { src = a6; off = OFF_WSG2; Kd = 256; g = i - 43008; }
  else                { src = a7; off = OFF_WSC2; Kd = 256; g = i - 51200; }
  const int KS   = Kd >> 4;
  const int tile = g / (KS * 64);
  const int rem  = g - tile * (KS * 64);
  const int ks   = rem >> 6;
  const int ln   = rem & 63;
  const float* sp = src + (size_t)(tile * 32 + (ln & 31)) * Kd + ks * 16 + (ln >> 5) * 8;
  #pragma unroll
  for (int j = 0; j < 8; ++j) out[off + (size_t)g * 8 + j] = f2bfu(sp[j]);
}

// single-matrix GEMM pass, one 32-row m-tile
template<int KS>
static __device__ __forceinline__ void gemm1(const unsigned short* __restrict__ Wt,
                                             const unsigned short* __restrict__ sIn,
                                             int l31, int kg, int xr, f32x16& acc)
{
  #pragma unroll 4
  for (int ks = 0; ks < KS; ++ks) {
    const bf16x8 Wc = *(const bf16x8*)(Wt + ks * 512);
    const bf16x8 A  = *(const bf16x8*)(sIn + l31 * LSTR + (((ks * 16) + kg * 8) ^ xr));
    acc = mfma32(A, Wc, acc);
  }
}

// paired GEMM pass: two weight matrices sharing the A operand stream
template<int KS>
static __device__ __forceinline__ void gemm1p(const unsigned short* __restrict__ Wa,
                                              const unsigned short* __restrict__ Wb,
                                              const unsigned short* __restrict__ sIn,
                                              int l31, int kg, int xr,
                                              f32x16& u, f32x16& s)
{
  #pragma unroll 4
  for (int ks = 0; ks < KS; ++ks) {
    const bf16x8 wa = *(const bf16x8*)(Wa + ks * 512);
    const bf16x8 wb = *(const bf16x8*)(Wb + ks * 512);
    const bf16x8 A  = *(const bf16x8*)(sIn + l31 * LSTR + (((ks * 16) + kg * 8) ^ xr));
    u = mfma32(A, wa, u);
    s = mfma32(A, wb, s);
  }
}

// b = silu(u) * s -> bf16 LDS (one m-tile)
static __device__ __forceinline__ void storeSilu1(unsigned short* dst, const f32x16 u,
                                                  const f32x16 s, int kg, int ocol)
{
  #pragma unroll
  for (int i = 0; i < 16; ++i) {
    const float x = u[i];
    dst[lidx(crow(i, kg), ocol)] = f2bfu(x * sigm(x) * s[i]);
  }
}

// write 8 packed words (one m-tile) to LDS
static __device__ __forceinline__ void storePk1(unsigned short* dst, const unsigned* xp,
                                                int kg, int ocol)
{
  #pragma unroll
  for (int p = 0; p < 8; ++p) {
    const int row0 = crow(2 * p, kg);
    const unsigned pk = xp[p];
    dst[lidx(row0,     ocol)] = (unsigned short)(pk & 0xffff);
    dst[lidx(row0 + 1, ocol)] = (unsigned short)(pk >> 16);
  }
}

// ---------------------------------------------------------------------------
// Main fused kernel. 32 rows/block, 256 threads (4 waves), 32 KB LDS ->
// 5 blocks/CU. Wave w owns ocols [64w, 64w+64) as 2 col-tiles; 1 m-tile.
// LayerNorms use 8-threads-per-row (3-step shfl), b128 LDS access.
// ---------------------------------------------------------------------------
__global__ __launch_bounds__(THREADS, 5)
void iab_rows_mfma(
    const float* __restrict__ v, const float* __restrict__ af,
    const float* __restrict__ fw, const float* __restrict__ fb,
    const float* __restrict__ ln1g, const float* __restrict__ ln1b,
    const float* __restrict__ bsig1,
    const float* __restrict__ ln2g, const float* __restrict__ ln2b,
    const float* __restrict__ bsig2,
    const float* __restrict__ outb,
    const unsigned short* __restrict__ wc,
    float* __restrict__ scores, int N)
{
  __shared__ __align__(16) unsigned short sA[ROWS * LSTR];  // xhat1 -> x2 -> xhat2 -> xf
  __shared__ __align__(16) unsigned short sB[ROWS * LSTR];  // b1 -> b2

  const int t    = threadIdx.x;
  const int w    = t >> 6;
  const int lane = t & 63;
  const int l31  = lane & 31;
  const int kg   = lane >> 5;
  const int xr   = (lane & 7) << 3;
  const int row0 = blockIdx.x * ROWS;

  // ---- P0: features + LN1, 8 threads per row ----
  {
    const int r   = t >> 3;          // 0..31
    const int sub = t & 7;
    const int g   = row0 + r;
    const int xrr = (r & 7) << 3;
    float vx = 0.f, vy = 0.f, vz = 0.f;
    if (g < N) {
      vx = v[3 * (size_t)g + 0];
      vy = v[3 * (size_t)g + 1];
      vz = v[3 * (size_t)g + 2];
    }
    const float nrm = sqrtf(vx * vx + vy * vy + vz * vz);
    float e[24];
    {
      const float4 fwa = *(const float4*)(fw + sub * 8);
      const float4 fwb = *(const float4*)(fw + sub * 8 + 4);
      const float4 fba = *(const float4*)(fb + sub * 8);
      const float4 fbb = *(const float4*)(fb + sub * 8 + 4);
      e[0] = __cosf(6.283185307179586f * (nrm * fwa.x + fba.x));
      e[1] = __cosf(6.283185307179586f * (nrm * fwa.y + fba.y));
      e[2] = __cosf(6.283185307179586f * (nrm * fwa.z + fba.z));
      e[3] = __cosf(6.283185307179586f * (nrm * fwa.w + fba.w));
      e[4] = __cosf(6.283185307179586f * (nrm * fwb.x + fbb.x));
      e[5] = __cosf(6.283185307179586f * (nrm * fwb.y + fbb.y));
      e[6] = __cosf(6.283185307179586f * (nrm * fwb.z + fbb.z));
      e[7] = __cosf(6.283185307179586f * (nrm * fwb.w + fbb.w));
    }
    if (g < N) {
      const float* ap = af + (size_t)g * 128 + sub * 8;
      const float4 a0 = *(const float4*)(ap);
      const float4 a1 = *(const float4*)(ap + 4);
      const float4 a2 = *(const float4*)(ap + 64);
      const float4 a3 = *(const float4*)(ap + 68);
      e[8]  = a0.x; e[9]  = a0.y; e[10] = a0.z; e[11] = a0.w;
      e[12] = a1.x; e[13] = a1.y; e[14] = a1.z; e[15] = a1.w;
      e[16] = a2.x; e[17] = a2.y; e[18] = a2.z; e[19] = a2.w;
      e[20] = a3.x; e[21] = a3.y; e[22] = a3.z; e[23] = a3.w;
    } else {
      #pragma unroll
      for (int j = 8; j < 24; ++j) e[j] = 0.f;
    }
    float s = 0.f, sq = 0.f;
    #pragma unroll
    for (int j = 0; j < 24; ++j) { s += e[j]; sq += e[j] * e[j]; }
    #pragma unroll
    for (int o = 1; o < 8; o <<= 1) {
      s  += __shfl_xor(s,  o);
      sq += __shfl_xor(sq, o);
    }
    const float mean = s * (1.f / 192.f);
    const float var  = fmaxf(sq * (1.f / 192.f) - mean * mean, 0.f);
    const float rstd = rsqrtf(var + 1e-5f);
    #pragma unroll
    for (int ch = 0; ch < 3; ++ch) {
      const int base = ch * 64 + sub * 8;
      const float4 ga = *(const float4*)(ln1g + base);
      const float4 gb = *(const float4*)(ln1g + base + 4);
      const float4 oa = *(const float4*)(ln1b + base);
      const float4 ob = *(const float4*)(ln1b + base + 4);
      u16x8 p;
      p[0] = f2bfu((e[ch*8+0] - mean) * rstd * ga.x + oa.x);
      p[1] = f2bfu((e[ch*8+1] - mean) * rstd * ga.y + oa.y);
      p[2] = f2bfu((e[ch*8+2] - mean) * rstd * ga.z + oa.z);
      p[3] = f2bfu((e[ch*8+3] - mean) * rstd * ga.w + oa.w);
      p[4] = f2bfu((e[ch*8+4] - mean) * rstd * gb.x + ob.x);
      p[5] = f2bfu((e[ch*8+5] - mean) * rstd * gb.y + ob.y);
      p[6] = f2bfu((e[ch*8+6] - mean) * rstd * gb.z + ob.z);
      p[7] = f2bfu((e[ch*8+7] - mean) * rstd * gb.w + ob.w);
      *(u16x8*)(sA + r * LSTR + (base ^ xrr)) = p;
    }
  }
  __syncthreads();

  unsigned x2p[16];   // packed x2 (TB1 out), [c*8 + p]
  unsigned sgp[16];   // packed sigmoid gate

  // ---- B1: b1 = silu(x@Wsw1)*(x@Wss1) -> sB (2 col-tiles) ----
  #pragma unroll
  for (int c = 0; c < 2; ++c) {
    const int ocol = w * 64 + c * 32 + l31;
    const int T = w * 2 + c;
    f32x16 u{}, s{};
    gemm1p<12>(wc + OFF_WSW1 + T * 12 * 512 + lane * 8,
               wc + OFF_WSS1 + T * 12 * 512 + lane * 8, sA, l31, kg, xr, u, s);
    storeSilu1(sB, u, s, kg, ocol);
  }

  // ---- C-sg: sig = sigmoid(x@Wsg1 + b) (reads sA only; pre-barrier) ----
  #pragma unroll
  for (int c = 0; c < 2; ++c) {
    const int ocol = w * 64 + c * 32 + l31;
    const int T = w * 2 + c;
    f32x16 gacc{};
    gemm1<12>(wc + OFF_WSG1 + T * 12 * 512 + lane * 8, sA, l31, kg, xr, gacc);
    const float bias = bsig1[ocol];
    #pragma unroll
    for (int p = 0; p < 8; ++p)
      sgp[c * 8 + p] = pk2(sigm(gacc[2*p] + bias), sigm(gacc[2*p+1] + bias));
  }
  __syncthreads();   // b1 visible; all xhat1 reads complete

  // ---- C-sc: c = b1@Wsc1; x2 = sig*c -> regs + sA ----
  #pragma unroll
  for (int c = 0; c < 2; ++c) {
    const int ocol = w * 64 + c * 32 + l31;
    const int T = w * 2 + c;
    f32x16 cacc{};
    gemm1<16>(wc + OFF_WSC1 + T * 16 * 512 + lane * 8, sB, l31, kg, xr, cacc);
    #pragma unroll
    for (int p = 0; p < 8; ++p)
      x2p[c * 8 + p] = pk2(lo16(sgp[c*8+p]) * cacc[2*p],
                           hi16(sgp[c*8+p]) * cacc[2*p+1]);
    storePk1(sA, x2p + c * 8, kg, ocol);
  }
  __syncthreads();

  // ---- LN2: 8 threads per row over sA ----
  {
    const int r   = t >> 3;
    const int sub = t & 7;
    const int xrr = (r & 7) << 3;
    u16x8 rv0 = *(const u16x8*)(sA + r * LSTR + ((sub * 32 +  0) ^ xrr));
    u16x8 rv1 = *(const u16x8*)(sA + r * LSTR + ((sub * 32 +  8) ^ xrr));
    u16x8 rv2 = *(const u16x8*)(sA + r * LSTR + ((sub * 32 + 16) ^ xrr));
    u16x8 rv3 = *(const u16x8*)(sA + r * LSTR + ((sub * 32 + 24) ^ xrr));
    float e[32];
    #pragma unroll
    for (int j = 0; j < 8; ++j) {
      e[j]      = bfu2f(rv0[j]);
      e[8 + j]  = bfu2f(rv1[j]);
      e[16 + j] = bfu2f(rv2[j]);
      e[24 + j] = bfu2f(rv3[j]);
    }
    float s = 0.f, sq = 0.f;
    #pragma unroll
    for (int j = 0; j < 32; ++j) { s += e[j]; sq += e[j] * e[j]; }
    #pragma unroll
    for (int o = 1; o < 8; o <<= 1) {
      s  += __shfl_xor(s,  o);
      sq += __shfl_xor(sq, o);
    }
    const float mean = s * (1.f / 256.f);
    const float var  = fmaxf(sq * (1.f / 256.f) - mean * mean, 0.f);
    const float rstd = rsqrtf(var + 1e-5f);
    #pragma unroll
    for (int c = 0; c < 4; ++c) {
      const int base = sub * 32 + c * 8;
      const float4 ga = *(const float4*)(ln2g + base);
      const float4 gb = *(const float4*)(ln2g + base + 4);
      const float4 oa = *(const float4*)(ln2b + base);
      const float4 ob = *(const float4*)(ln2b + base + 4);
      u16x8 p;
      p[0] = f2bfu((e[c*8+0] - mean) * rstd * ga.x + oa.x);
      p[1] = f2bfu((e[c*8+1] - mean) * rstd * ga.y + oa.y);
      p[2] = f2bfu((e[c*8+2] - mean) * rstd * ga.z + oa.z);
      p[3] = f2bfu((e[c*8+3] - mean) * rstd * ga.w + oa.w);
      p[4] = f2bfu((e[c*8+4] - mean) * rstd * gb.x + ob.x);
      p[5] = f2bfu((e[c*8+5] - mean) * rstd * gb.y + ob.y);
      p[6] = f2bfu((e[c*8+6] - mean) * rstd * gb.z + ob.z);
      p[7] = f2bfu((e[c*8+7] - mean) * rstd * gb.w + ob.w);
      *(u16x8*)(sA + r * LSTR + (base ^ xrr)) = p;
    }
  }
  __syncthreads();

  // ---- D1: b2 = silu(xhat2@Wsw2)*(xhat2@Wss2) -> sB ----
  #pragma unroll
  for (int c = 0; c < 2; ++c) {
    const int ocol = w * 64 + c * 32 + l31;
    const int T = w * 2 + c;
    f32x16 u{}, s{};
    gemm1p<16>(wc + OFF_WSW2 + T * 16 * 512 + lane * 8,
               wc + OFF_WSS2 + T * 16 * 512 + lane * 8, sA, l31, kg, xr, u, s);
    storeSilu1(sB, u, s, kg, ocol);
  }

  // ---- D23-sg: sig2 = sigmoid(xhat2@Wsg2 + b) (pre-barrier) ----
  #pragma unroll
  for (int c = 0; c < 2; ++c) {
    const int ocol = w * 64 + c * 32 + l31;
    const int T = w * 2 + c;
    f32x16 gacc{};
    gemm1<16>(wc + OFF_WSG2 + T * 16 * 512 + lane * 8, sA, l31, kg, xr, gacc);
    const float bias = bsig2[ocol];
    #pragma unroll
    for (int p = 0; p < 8; ++p)
      sgp[c * 8 + p] = pk2(sigm(gacc[2*p] + bias), sigm(gacc[2*p+1] + bias));
  }
  __syncthreads();   // b2 visible; all xhat2 reads complete

  // ---- D23-sc: c2 = b2@Wsc2; xf = x2 + sig2*c2 -> sA ----
  #pragma unroll
  for (int c = 0; c < 2; ++c) {
    const int ocol = w * 64 + c * 32 + l31;
    const int T = w * 2 + c;
    f32x16 cacc{};
    gemm1<16>(wc + OFF_WSC2 + T * 16 * 512 + lane * 8, sB, l31, kg, xr, cacc);
    #pragma unroll
    for (int p = 0; p < 8; ++p)
      x2p[c * 8 + p] = pk2(lo16(x2p[c*8+p]) + lo16(sgp[c*8+p]) * cacc[2*p],
                           hi16(x2p[c*8+p]) + hi16(sgp[c*8+p]) * cacc[2*p+1]);
    storePk1(sA, x2p + c * 8, kg, ocol);
  }
  __syncthreads();

  // ---- F: scores = xf @ out_w^T + out_b via MFMA (wave 0) ----
  if (w == 0) {
    const unsigned short* WtF = wc + OFF_WOUT + (size_t)lane * 8;
    f32x16 c{};
    #pragma unroll 4
    for (int ks = 0; ks < 16; ++ks) {
      const bf16x8 wf = *(const bf16x8*)(WtF + ks * 512);
      const bf16x8 A  = *(const bf16x8*)(sA + l31 * LSTR + (((ks * 16) + kg * 8) ^ xr));
      c = mfma32(A, wf, c);
    }
    if (l31 < 4) {
      const float bias = outb[l31];
      #pragma unroll
      for (int i = 0; i < 16; ++i) {
        const int g = row0 + crow(i, kg);
        if (g < N) scores[(size_t)g * 4 + l31] = c[i] + bias;
      }
    }
  }
}

// ---------------------------------------------------------------------------
// Segment softmax + weighted 3-vector pooling (sorted indices, wave/segment).
// ---------------------------------------------------------------------------
__device__ __forceinline__ int iab_lower_bound(const int* __restrict__ a, int n, int key)
{
  int lo = 0, hi = n;
  while (lo < hi) {
    const int mid = (lo + hi) >> 1;
    if (a[mid] < key) lo = mid + 1; else hi = mid;
  }
  return lo;
}

__global__ __launch_bounds__(256)
void iab_segpool_kernel(const float* __restrict__ scores,
                        const float* __restrict__ v,
                        const int* __restrict__ gidx,
                        float* __restrict__ out, int N, int E)
{
  const int seg  = blockIdx.x * 4 + (threadIdx.x >> 6);
  const int lane = threadIdx.x & 63;
  if (seg >= E) return;

  const int lo = iab_lower_bound(gidx, N, seg);
  const int hi = iab_lower_bound(gidx, N, seg + 1);

  const int h  = lane & 3;
  const int ro = lane >> 2;

  float m = -INFINITY;
  for (int base = lo; base < hi; base += 16) {
    const int r = base + ro;
    if (r < hi) m = fmaxf(m, scores[(size_t)r * 4 + h]);
  }
  #pragma unroll
  for (int o = 4; o < 64; o <<= 1) m = fmaxf(m, __shfl_xor(m, o));

  float ssum = 0.f, w0 = 0.f, w1 = 0.f, w2 = 0.f;
  for (int base = lo; base < hi; base += 16) {
    const int r = base + ro;
    if (r < hi) {
      const float e = expf(scores[(size_t)r * 4 + h] - m);
      ssum += e;
      w0 += e * v[3 * (size_t)r + 0];
      w1 += e * v[3 * (size_t)r + 1];
      w2 += e * v[3 * (size_t)r + 2];
    }
  }
  #pragma unroll
  for (int o = 4; o < 64; o <<= 1) {
    ssum += __shfl_xor(ssum, o);
    w0   += __shfl_xor(w0, o);
    w1   += __shfl_xor(w1, o);
    w2   += __shfl_xor(w2, o);
  }

  if (ro == 0) {
    const float inv = (hi > lo) ? (1.f / ssum) : 0.f;
    out[(size_t)seg * 12 + h * 3 + 0] = w0 * inv;
    out[(size_t)seg * 12 + h * 3 + 1] = w1 * inv;
    out[(size_t)seg * 12 + h * 3 + 2] = w2 * inv;
  }
}

// ---------------------------------------------------------------------------
extern "C" void kernel_launch(void* const* d_in, const int* in_sizes, int n_in,
                              void* d_out, int out_size, void* d_ws, size_t ws_size,
                              hipStream_t stream)
{
  const float* v     = (const float*)d_in[0];
  const float* af    = (const float*)d_in[1];
  const int*   gidx  = (const int*)  d_in[2];
  const float* fw    = (const float*)d_in[4];
  const float* fb    = (const float*)d_in[5];
  const float* ln1g  = (const float*)d_in[6];
  const float* ln1b  = (const float*)d_in[7];
  const float* wsw1  = (const float*)d_in[8];
  const float* wss1  = (const float*)d_in[9];
  const float* wsig1 = (const float*)d_in[10];
  const float* bsig1 = (const float*)d_in[11];
  const float* wsc1  = (const float*)d_in[12];
  const float* ln2g  = (const float*)d_in[13];
  const float* ln2b  = (const float*)d_in[14];
  const float* wsw2  = (const float*)d_in[15];
  const float* wss2  = (const float*)d_in[16];
  const float* wsig2 = (const float*)d_in[17];
  const float* bsig2 = (const float*)d_in[18];
  const float* wsc2  = (const float*)d_in[19];
  const float* outw  = (const float*)d_in[20];
  const float* outb  = (const float*)d_in[21];

  const int N = in_sizes[0] / 3;
  const int E = out_size / 12;

  float* scores = (float*)d_ws;                                   // N*4 f32 = 16 MB
  unsigned short* wcv = (unsigned short*)((char*)d_ws + (size_t)N * 4 * sizeof(float));

  hipLaunchKernelGGL(iab_wconv_kernel, dim3((NGRP_ALL + 255) / 256), dim3(256), 0, stream,
                     wsw1, wss1, wsig1, wsc1, wsw2, wss2, wsig2, wsc2, outw, wcv);

  hipLaunchKernelGGL(iab_rows_mfma, dim3((N + ROWS - 1) / ROWS), dim3(THREADS), 0, stream,
                     v, af, fw, fb, ln1g, ln1b, bsig1, ln2g, ln2b, bsig2, outb,
                     wcv, scores, N);

  hipLaunchKernelGGL(iab_segpool_kernel, dim3((E + 3) / 4), dim3(256), 0, stream,
                     scores, v, gidx, (float*)d_out, N, E);
}

// Round 8
// 2311.011 us; speedup vs baseline: 1.1268x; 1.1268x over previous
//
#include <hip/hip_runtime.h>
#include <math.h>

#define DIN   192
#define HD    256
#define ROWS  32
#define THREADS 256
#define LSTR  256

typedef __bf16 bf16_t;
typedef bf16_t bf16x8 __attribute__((ext_vector_type(8)));
typedef unsigned short u16x8 __attribute__((ext_vector_type(8)));
typedef float  f32x16 __attribute__((ext_vector_type(16)));

static __device__ __forceinline__ f32x16 mfma32(bf16x8 a, bf16x8 b, f32x16 c) {
  return __builtin_amdgcn_mfma_f32_32x32x16_bf16(a, b, c, 0, 0, 0);
}
static __device__ __forceinline__ unsigned short f2bfu(float f) {
  bf16_t h = (bf16_t)f; unsigned short u; __builtin_memcpy(&u, &h, 2); return u;
}
static __device__ __forceinline__ float bfu2f(unsigned short u) {
  unsigned x = ((unsigned)u) << 16; float f; __builtin_memcpy(&f, &x, 4); return f;
}
static __device__ __forceinline__ unsigned pk2(float a, float b) {
  return (unsigned)f2bfu(a) | ((unsigned)f2bfu(b) << 16);
}
static __device__ __forceinline__ float lo16(unsigned u) { return bfu2f((unsigned short)(u & 0xffff)); }
static __device__ __forceinline__ float hi16(unsigned u) { return bfu2f((unsigned short)(u >> 16)); }
static __device__ __forceinline__ float sigm(float x) {
  return __builtin_amdgcn_rcpf(1.f + __expf(-x));
}
// XOR-swizzled LDS element index (b16 granularity)
static __device__ __forceinline__ int lidx(int row, int col) {
  return row * LSTR + (col ^ ((row & 7) << 3));
}
// C-layout row for 32x32 MFMA (m74/m101): row = (r&3) + 8*(r>>2) + 4*kg
static __device__ __forceinline__ int crow(int r, int kg) {
  return (r & 3) + 8 * (r >> 2) + 4 * kg;
}

// bf16 weight regions (elements) in d_ws after scores buffer.
// Fragment order: ((tile*KS + ks)*64 + lane)*8 + j; tile=ocol>>5,
// lane=kg*32+(ocol&31), k=ks*16+kg*8+j. out_w padded 4->32 cols.
#define OFF_WSW1 0
#define OFF_WSS1 49152
#define OFF_WSG1 98304
#define OFF_WSC1 147456
#define OFF_WSW2 212992
#define OFF_WSS2 278528
#define OFF_WSG2 344064
#define OFF_WSC2 409600
#define OFF_WOUT 475136
#define NGRP_REORD 59392
#define NGRP_ALL   60416

__global__ void iab_wconv_kernel(const float* __restrict__ a0, const float* __restrict__ a1,
                                 const float* __restrict__ a2, const float* __restrict__ a3,
                                 const float* __restrict__ a4, const float* __restrict__ a5,
                                 const float* __restrict__ a6, const float* __restrict__ a7,
                                 const float* __restrict__ a8, unsigned short* __restrict__ out)
{
  const int i = blockIdx.x * 256 + threadIdx.x;
  if (i >= NGRP_ALL) return;
  if (i >= NGRP_REORD) {                       // out_w padded fragment tile
    const int g  = i - NGRP_REORD;             // [0, 1024)
    const int ks = g >> 6;
    const int ln = g & 63;
    const int col = ln & 31;
    const int kg  = ln >> 5;
    #pragma unroll
    for (int j = 0; j < 8; ++j) {
      const float vv = (col < 4) ? a8[col * 256 + ks * 16 + kg * 8 + j] : 0.f;
      out[OFF_WOUT + (size_t)g * 8 + j] = f2bfu(vv);
    }
    return;
  }
  const float* src; int off, Kd, g;
  if      (i < 6144)  { src = a0; off = OFF_WSW1; Kd = 192; g = i; }
  else if (i < 12288) { src = a1; off = OFF_WSS1; Kd = 192; g = i - 6144; }
  else if (i < 18432) { src = a2; off = OFF_WSG1; Kd = 192; g = i - 12288; }
  else if (i < 26624) { src = a3; off = OFF_WSC1; Kd = 256; g = i - 18432; }
  else if (i < 34816) { src = a4; off = OFF_WSW2; Kd = 256; g = i - 26624; }
  else if (i < 43008) { src = a5; off = OFF_WSS2; Kd = 256; g = i - 34816; }
  else if (i < 51200) { src = a6; off = OFF_WSG2; Kd = 256; g = i - 43008; }
  else                { src = a7; off = OFF_WSC2; Kd = 256; g = i - 51200; }
  const int KS   = Kd >> 4;
  const int tile = g / (KS * 64);
  const int rem  = g - tile * (KS * 64);
  const int ks   = rem >> 6;
  const int ln   = rem & 63;
  const float* sp = src + (size_t)(tile * 32 + (ln & 31)) * Kd + ks * 16 + (ln >> 5) * 8;
  #pragma unroll
  for (int j = 0; j < 8; ++j) out[off + (size_t)g * 8 + j] = f2bfu(sp[j]);
}

// single-matrix GEMM pass, one 32-row m-tile
template<int KS>
static __device__ __forceinline__ void gemm1(const unsigned short* __restrict__ Wt,
                                             const unsigned short* __restrict__ sIn,
                                             int l31, int kg, int xr, f32x16& acc)
{
  #pragma unroll 4
  for (int ks = 0; ks < KS; ++ks) {
    const bf16x8 Wc = *(const bf16x8*)(Wt + ks * 512);
    const bf16x8 A  = *(const bf16x8*)(sIn + l31 * LSTR + (((ks * 16) + kg * 8) ^ xr));
    acc = mfma32(A, Wc, acc);
  }
}

// paired GEMM pass: two weight matrices sharing the A operand stream
template<int KS>
static __device__ __forceinline__ void gemm1p(const unsigned short* __restrict__ Wa,
                                              const unsigned short* __restrict__ Wb,
                                              const unsigned short* __restrict__ sIn,
                                              int l31, int kg, int xr,
                                              f32x16& u, f32x16& s)
{
  #pragma unroll 4
  for (int ks = 0; ks < KS; ++ks) {
    const bf16x8 wa = *(const bf16x8*)(Wa + ks * 512);
    const bf16x8 wb = *(const bf16x8*)(Wb + ks * 512);
    const bf16x8 A  = *(const bf16x8*)(sIn + l31 * LSTR + (((ks * 16) + kg * 8) ^ xr));
    u = mfma32(A, wa, u);
    s = mfma32(A, wb, s);
  }
}

// b = silu(u) * s -> bf16 LDS (one m-tile)
static __device__ __forceinline__ void storeSilu1(unsigned short* dst, const f32x16 u,
                                                  const f32x16 s, int kg, int ocol)
{
  #pragma unroll
  for (int i = 0; i < 16; ++i) {
    const float x = u[i];
    dst[lidx(crow(i, kg), ocol)] = f2bfu(x * sigm(x) * s[i]);
  }
}

// write 8 packed words (one m-tile) to LDS
static __device__ __forceinline__ void storePk1(unsigned short* dst, const unsigned* xp,
                                                int kg, int ocol)
{
  #pragma unroll
  for (int p = 0; p < 8; ++p) {
    const int row0 = crow(2 * p, kg);
    const unsigned pk = xp[p];
    dst[lidx(row0,     ocol)] = (unsigned short)(pk & 0xffff);
    dst[lidx(row0 + 1, ocol)] = (unsigned short)(pk >> 16);
  }
}

// ---------------------------------------------------------------------------
// Main fused kernel. 32 rows/block, 256 threads (4 waves), 32 KB LDS.
// __launch_bounds__(256,4): 4 waves/EU -> 4 blocks/CU (16 waves), VGPR cap
// 128 (the feasible HW step; (256,5) forced 48 regs -> spills, R7).
// Wave w owns ocols [64w, 64w+64) as 2 col-tiles; 1 m-tile.
// ---------------------------------------------------------------------------
__global__ __launch_bounds__(THREADS, 4)
void iab_rows_mfma(
    const float* __restrict__ v, const float* __restrict__ af,
    const float* __restrict__ fw, const float* __restrict__ fb,
    const float* __restrict__ ln1g, const float* __restrict__ ln1b,
    const float* __restrict__ bsig1,
    const float* __restrict__ ln2g, const float* __restrict__ ln2b,
    const float* __restrict__ bsig2,
    const float* __restrict__ outb,
    const unsigned short* __restrict__ wc,
    float* __restrict__ scores, int N)
{
  __shared__ __align__(16) unsigned short sA[ROWS * LSTR];  // xhat1 -> x2 -> xhat2 -> xf
  __shared__ __align__(16) unsigned short sB[ROWS * LSTR];  // b1 -> b2

  const int t    = threadIdx.x;
  const int w    = t >> 6;
  const int lane = t & 63;
  const int l31  = lane & 31;
  const int kg   = lane >> 5;
  const int xr   = (lane & 7) << 3;
  const int row0 = blockIdx.x * ROWS;

  // ---- P0: features + LN1, 8 threads per row ----
  {
    const int r   = t >> 3;          // 0..31
    const int sub = t & 7;
    const int g   = row0 + r;
    const int xrr = (r & 7) << 3;
    float vx = 0.f, vy = 0.f, vz = 0.f;
    if (g < N) {
      vx = v[3 * (size_t)g + 0];
      vy = v[3 * (size_t)g + 1];
      vz = v[3 * (size_t)g + 2];
    }
    const float nrm = sqrtf(vx * vx + vy * vy + vz * vz);
    float e[24];
    {
      const float4 fwa = *(const float4*)(fw + sub * 8);
      const float4 fwb = *(const float4*)(fw + sub * 8 + 4);
      const float4 fba = *(const float4*)(fb + sub * 8);
      const float4 fbb = *(const float4*)(fb + sub * 8 + 4);
      e[0] = __cosf(6.283185307179586f * (nrm * fwa.x + fba.x));
      e[1] = __cosf(6.283185307179586f * (nrm * fwa.y + fba.y));
      e[2] = __cosf(6.283185307179586f * (nrm * fwa.z + fba.z));
      e[3] = __cosf(6.283185307179586f * (nrm * fwa.w + fba.w));
      e[4] = __cosf(6.283185307179586f * (nrm * fwb.x + fbb.x));
      e[5] = __cosf(6.283185307179586f * (nrm * fwb.y + fbb.y));
      e[6] = __cosf(6.283185307179586f * (nrm * fwb.z + fbb.z));
      e[7] = __cosf(6.283185307179586f * (nrm * fwb.w + fbb.w));
    }
    if (g < N) {
      const float* ap = af + (size_t)g * 128 + sub * 8;
      const float4 a0 = *(const float4*)(ap);
      const float4 a1 = *(const float4*)(ap + 4);
      const float4 a2 = *(const float4*)(ap + 64);
      const float4 a3 = *(const float4*)(ap + 68);
      e[8]  = a0.x; e[9]  = a0.y; e[10] = a0.z; e[11] = a0.w;
      e[12] = a1.x; e[13] = a1.y; e[14] = a1.z; e[15] = a1.w;
      e[16] = a2.x; e[17] = a2.y; e[18] = a2.z; e[19] = a2.w;
      e[20] = a3.x; e[21] = a3.y; e[22] = a3.z; e[23] = a3.w;
    } else {
      #pragma unroll
      for (int j = 8; j < 24; ++j) e[j] = 0.f;
    }
    float s = 0.f, sq = 0.f;
    #pragma unroll
    for (int j = 0; j < 24; ++j) { s += e[j]; sq += e[j] * e[j]; }
    #pragma unroll
    for (int o = 1; o < 8; o <<= 1) {
      s  += __shfl_xor(s,  o);
      sq += __shfl_xor(sq, o);
    }
    const float mean = s * (1.f / 192.f);
    const float var  = fmaxf(sq * (1.f / 192.f) - mean * mean, 0.f);
    const float rstd = rsqrtf(var + 1e-5f);
    #pragma unroll
    for (int ch = 0; ch < 3; ++ch) {
      const int base = ch * 64 + sub * 8;
      const float4 ga = *(const float4*)(ln1g + base);
      const float4 gb = *(const float4*)(ln1g + base + 4);
      const float4 oa = *(const float4*)(ln1b + base);
      const float4 ob = *(const float4*)(ln1b + base + 4);
      u16x8 p;
      p[0] = f2bfu((e[ch*8+0] - mean) * rstd * ga.x + oa.x);
      p[1] = f2bfu((e[ch*8+1] - mean) * rstd * ga.y + oa.y);
      p[2] = f2bfu((e[ch*8+2] - mean) * rstd * ga.z + oa.z);
      p[3] = f2bfu((e[ch*8+3] - mean) * rstd * ga.w + oa.w);
      p[4] = f2bfu((e[ch*8+4] - mean) * rstd * gb.x + ob.x);
      p[5] = f2bfu((e[ch*8+5] - mean) * rstd * gb.y + ob.y);
      p[6] = f2bfu((e[ch*8+6] - mean) * rstd * gb.z + ob.z);
      p[7] = f2bfu((e[ch*8+7] - mean) * rstd * gb.w + ob.w);
      *(u16x8*)(sA + r * LSTR + (base ^ xrr)) = p;
    }
  }
  __syncthreads();

  unsigned x2p[16];   // packed x2 (TB1 out), [c*8 + p]
  unsigned sgp[16];   // packed sigmoid gate

  // ---- B1: b1 = silu(x@Wsw1)*(x@Wss1) -> sB (2 col-tiles) ----
  #pragma unroll
  for (int c = 0; c < 2; ++c) {
    const int ocol = w * 64 + c * 32 + l31;
    const int T = w * 2 + c;
    f32x16 u{}, s{};
    gemm1p<12>(wc + OFF_WSW1 + T * 12 * 512 + lane * 8,
               wc + OFF_WSS1 + T * 12 * 512 + lane * 8, sA, l31, kg, xr, u, s);
    storeSilu1(sB, u, s, kg, ocol);
  }

  // ---- C-sg: sig = sigmoid(x@Wsg1 + b) (reads sA only; pre-barrier) ----
  #pragma unroll
  for (int c = 0; c < 2; ++c) {
    const int ocol = w * 64 + c * 32 + l31;
    const int T = w * 2 + c;
    f32x16 gacc{};
    gemm1<12>(wc + OFF_WSG1 + T * 12 * 512 + lane * 8, sA, l31, kg, xr, gacc);
    const float bias = bsig1[ocol];
    #pragma unroll
    for (int p = 0; p < 8; ++p)
      sgp[c * 8 + p] = pk2(sigm(gacc[2*p] + bias), sigm(gacc[2*p+1] + bias));
  }
  __syncthreads();   // b1 visible; all xhat1 reads complete

  // ---- C-sc: c = b1@Wsc1; x2 = sig*c -> regs + sA ----
  #pragma unroll
  for (int c = 0; c < 2; ++c) {
    const int ocol = w * 64 + c * 32 + l31;
    const int T = w * 2 + c;
    f32x16 cacc{};
    gemm1<16>(wc + OFF_WSC1 + T * 16 * 512 + lane * 8, sB, l31, kg, xr, cacc);
    #pragma unroll
    for (int p = 0; p < 8; ++p)
      x2p[c * 8 + p] = pk2(lo16(sgp[c*8+p]) * cacc[2*p],
                           hi16(sgp[c*8+p]) * cacc[2*p+1]);
    storePk1(sA, x2p + c * 8, kg, ocol);
  }
  __syncthreads();

  // ---- LN2: 8 threads per row over sA ----
  {
    const int r   = t >> 3;
    const int sub = t & 7;
    const int xrr = (r & 7) << 3;
    u16x8 rv0 = *(const u16x8*)(sA + r * LSTR + ((sub * 32 +  0) ^ xrr));
    u16x8 rv1 = *(const u16x8*)(sA + r * LSTR + ((sub * 32 +  8) ^ xrr));
    u16x8 rv2 = *(const u16x8*)(sA + r * LSTR + ((sub * 32 + 16) ^ xrr));
    u16x8 rv3 = *(const u16x8*)(sA + r * LSTR + ((sub * 32 + 24) ^ xrr));
    float e[32];
    #pragma unroll
    for (int j = 0; j < 8; ++j) {
      e[j]      = bfu2f(rv0[j]);
      e[8 + j]  = bfu2f(rv1[j]);
      e[16 + j] = bfu2f(rv2[j]);
      e[24 + j] = bfu2f(rv3[j]);
    }
    float s = 0.f, sq = 0.f;
    #pragma unroll
    for (int j = 0; j < 32; ++j) { s += e[j]; sq += e[j] * e[j]; }
    #pragma unroll
    for (int o = 1; o < 8; o <<= 1) {
      s  += __shfl_xor(s,  o);
      sq += __shfl_xor(sq, o);
    }
    const float mean = s * (1.f / 256.f);
    const float var  = fmaxf(sq * (1.f / 256.f) - mean * mean, 0.f);
    const float rstd = rsqrtf(var + 1e-5f);
    #pragma unroll
    for (int c = 0; c < 4; ++c) {
      const int base = sub * 32 + c * 8;
      const float4 ga = *(const float4*)(ln2g + base);
      const float4 gb = *(const float4*)(ln2g + base + 4);
      const float4 oa = *(const float4*)(ln2b + base);
      const float4 ob = *(const float4*)(ln2b + base + 4);
      u16x8 p;
      p[0] = f2bfu((e[c*8+0] - mean) * rstd * ga.x + oa.x);
      p[1] = f2bfu((e[c*8+1] - mean) * rstd * ga.y + oa.y);
      p[2] = f2bfu((e[c*8+2] - mean) * rstd * ga.z + oa.z);
      p[3] = f2bfu((e[c*8+3] - mean) * rstd * ga.w + oa.w);
      p[4] = f2bfu((e[c*8+4] - mean) * rstd * gb.x + ob.x);
      p[5] = f2bfu((e[c*8+5] - mean) * rstd * gb.y + ob.y);
      p[6] = f2bfu((e[c*8+6] - mean) * rstd * gb.z + ob.z);
      p[7] = f2bfu((e[c*8+7] - mean) * rstd * gb.w + ob.w);
      *(u16x8*)(sA + r * LSTR + (base ^ xrr)) = p;
    }
  }
  __syncthreads();

  // ---- D1: b2 = silu(xhat2@Wsw2)*(xhat2@Wss2) -> sB ----
  #pragma unroll
  for (int c = 0; c < 2; ++c) {
    const int ocol = w * 64 + c * 32 + l31;
    const int T = w * 2 + c;
    f32x16 u{}, s{};
    gemm1p<16>(wc + OFF_WSW2 + T * 16 * 512 + lane * 8,
               wc + OFF_WSS2 + T * 16 * 512 + lane * 8, sA, l31, kg, xr, u, s);
    storeSilu1(sB, u, s, kg, ocol);
  }

  // ---- D23-sg: sig2 = sigmoid(xhat2@Wsg2 + b) (pre-barrier) ----
  #pragma unroll
  for (int c = 0; c < 2; ++c) {
    const int ocol = w * 64 + c * 32 + l31;
    const int T = w * 2 + c;
    f32x16 gacc{};
    gemm1<16>(wc + OFF_WSG2 + T * 16 * 512 + lane * 8, sA, l31, kg, xr, gacc);
    const float bias = bsig2[ocol];
    #pragma unroll
    for (int p = 0; p < 8; ++p)
      sgp[c * 8 + p] = pk2(sigm(gacc[2*p] + bias), sigm(gacc[2*p+1] + bias));
  }
  __syncthreads();   // b2 visible; all xhat2 reads complete

  // ---- D23-sc: c2 = b2@Wsc2; xf = x2 + sig2*c2 -> sA ----
  #pragma unroll
  for (int c = 0; c < 2; ++c) {
    const int ocol = w * 64 + c * 32 + l31;
    const int T = w * 2 + c;
    f32x16 cacc{};
    gemm1<16>(wc + OFF_WSC2 + T * 16 * 512 + lane * 8, sB, l31, kg, xr, cacc);
    #pragma unroll
    for (int p = 0; p < 8; ++p)
      x2p[c * 8 + p] = pk2(lo16(x2p[c*8+p]) + lo16(sgp[c*8+p]) * cacc[2*p],
                           hi16(x2p[c*8+p]) + hi16(sgp[c*8+p]) * cacc[2*p+1]);
    storePk1(sA, x2p + c * 8, kg, ocol);
  }
  __syncthreads();

  // ---- F: scores = xf @ out_w^T + out_b via MFMA (wave 0) ----
  if (w == 0) {
    const unsigned short* WtF = wc + OFF_WOUT + (size_t)lane * 8;
    f32x16 c{};
    #pragma unroll 4
    for (int ks = 0; ks < 16; ++ks) {
      const bf16x8 wf = *(const bf16x8*)(WtF + ks * 512);
      const bf16x8 A  = *(const bf16x8*)(sA + l31 * LSTR + (((ks * 16) + kg * 8) ^ xr));
      c = mfma32(A, wf, c);
    }
    if (l31 < 4) {
      const float bias = outb[l31];
      #pragma unroll
      for (int i = 0; i < 16; ++i) {
        const int g = row0 + crow(i, kg);
        if (g < N) scores[(size_t)g * 4 + l31] = c[i] + bias;
      }
    }
  }
}

// ---------------------------------------------------------------------------
// Segment softmax + weighted 3-vector pooling (sorted indices, wave/segment).
// ---------------------------------------------------------------------------
__device__ __forceinline__ int iab_lower_bound(const int* __restrict__ a, int n, int key)
{
  int lo = 0, hi = n;
  while (lo < hi) {
    const int mid = (lo + hi) >> 1;
    if (a[mid] < key) lo = mid + 1; else hi = mid;
  }
  return lo;
}

__global__ __launch_bounds__(256)
void iab_segpool_kernel(const float* __restrict__ scores,
                        const float* __restrict__ v,
                        const int* __restrict__ gidx,
                        float* __restrict__ out, int N, int E)
{
  const int seg  = blockIdx.x * 4 + (threadIdx.x >> 6);
  const int lane = threadIdx.x & 63;
  if (seg >= E) return;

  const int lo = iab_lower_bound(gidx, N, seg);
  const int hi = iab_lower_bound(gidx, N, seg + 1);

  const int h  = lane & 3;
  const int ro = lane >> 2;

  float m = -INFINITY;
  for (int base = lo; base < hi; base += 16) {
    const int r = base + ro;
    if (r < hi) m = fmaxf(m, scores[(size_t)r * 4 + h]);
  }
  #pragma unroll
  for (int o = 4; o < 64; o <<= 1) m = fmaxf(m, __shfl_xor(m, o));

  float ssum = 0.f, w0 = 0.f, w1 = 0.f, w2 = 0.f;
  for (int base = lo; base < hi; base += 16) {
    const int r = base + ro;
    if (r < hi) {
      const float e = expf(scores[(size_t)r * 4 + h] - m);
      ssum += e;
      w0 += e * v[3 * (size_t)r + 0];
      w1 += e * v[3 * (size_t)r + 1];
      w2 += e * v[3 * (size_t)r + 2];
    }
  }
  #pragma unroll
  for (int o = 4; o < 64; o <<= 1) {
    ssum += __shfl_xor(ssum, o);
    w0   += __shfl_xor(w0, o);
    w1   += __shfl_xor(w1, o);
    w2   += __shfl_xor(w2, o);
  }

  if (ro == 0) {
    const float inv = (hi > lo) ? (1.f / ssum) : 0.f;
    out[(size_t)seg * 12 + h * 3 + 0] = w0 * inv;
    out[(size_t)seg * 12 + h * 3 + 1] = w1 * inv;
    out[(size_t)seg * 12 + h * 3 + 2] = w2 * inv;
  }
}

// ---------------------------------------------------------------------------
extern "C" void kernel_launch(void* const* d_in, const int* in_sizes, int n_in,
                              void* d_out, int out_size, void* d_ws, size_t ws_size,
                              hipStream_t stream)
{
  const float* v     = (const float*)d_in[0];
  const float* af    = (const float*)d_in[1];
  const int*   gidx  = (const int*)  d_in[2];
  const float* fw    = (const float*)d_in[4];
  const float* fb    = (const float*)d_in[5];
  const float* ln1g  = (const float*)d_in[6];
  const float* ln1b  = (const float*)d_in[7];
  const float* wsw1  = (const float*)d_in[8];
  const float* wss1  = (const float*)d_in[9];
  const float* wsig1 = (const float*)d_in[10];
  const float* bsig1 = (const float*)d_in[11];
  const float* wsc1  = (const float*)d_in[12];
  const float* ln2g  = (const float*)d_in[13];
  const float* ln2b  = (const float*)d_in[14];
  const float* wsw2  = (const float*)d_in[15];
  const float* wss2  = (const float*)d_in[16];
  const float* wsig2 = (const float*)d_in[17];
  const float* bsig2 = (const float*)d_in[18];
  const float* wsc2  = (const float*)d_in[19];
  const float* outw  = (const float*)d_in[20];
  const float* outb  = (const float*)d_in[21];

  const int N = in_sizes[0] / 3;
  const int E = out_size / 12;

  float* scores = (float*)d_ws;                                   // N*4 f32 = 16 MB
  unsigned short* wcv = (unsigned short*)((char*)d_ws + (size_t)N * 4 * sizeof(float));

  hipLaunchKernelGGL(iab_wconv_kernel, dim3((NGRP_ALL + 255) / 256), dim3(256), 0, stream,
                     wsw1, wss1, wsig1, wsc1, wsw2, wss2, wsig2, wsc2, outw, wcv);

  hipLaunchKernelGGL(iab_rows_mfma, dim3((N + ROWS - 1) / ROWS), dim3(THREADS), 0, stream,
                     v, af, fw, fb, ln1g, ln1b, bsig1, ln2g, ln2b, bsig2, outb,
                     wcv, scores, N);

  hipLaunchKernelGGL(iab_segpool_kernel, dim3((E + 3) / 4), dim3(256), 0, stream,
                     scores, v, gidx, (float*)d_out, N, E);
}